// Round 7
// baseline (101.977 us; speedup 1.0000x reference)
//
#include <hip/hip_runtime.h>
#include <hip/hip_bf16.h>
#include <stdint.h>

// Problem constants: B=4, L=2048, D=1024, vocab<32, N_GRAM=3
#define LSEQ 2048
#define DDIM 1024

typedef __attribute__((ext_vector_type(8))) short bf16x8;
typedef __attribute__((ext_vector_type(16))) float f32x16;

__device__ __forceinline__ ushort f2bf(float x) {
    uint32_t u = __builtin_bit_cast(uint32_t, x);
    u += 0x7fffu + ((u >> 16) & 1u);   // RNE (inputs finite/normal)
    return (ushort)(u >> 16);
}

// Fragment-major storage of a logical [R][1024] bf16 matrix F:
//   Ffrag[blk][k16][lane][j] = F[blk*32 + (lane&31)][k16*16 + (lane>>5)*8 + j]
// One wave fragment = 64 lanes x 16B = 1KB CONTIGUOUS -> a single perfectly
// coalesced global_load_dwordx4 per frag, straight into MFMA operand regs.
// byte offset:
__device__ __forceinline__ size_t frag_off(int blk, int k16, int lane) {
    return ((size_t)(blk * 64 + k16) * 64 + lane) * 16;
}

__device__ __forceinline__ int key_at(const int* __restrict__ ids, int base, int j) {
    return j >= 2 ? ((ids[base + j - 2] << 10) | (ids[base + j - 1] << 5) | ids[base + j]) : 0;
}

// ---------------- Kernel 1 (fused prep): pooled (blocks 0..8191) + W-transpose ----
// Outputs are written in fragment-major layout (frag_off).
__global__ __launch_bounds__(256) void prep(const float* __restrict__ H,
                                            const int* __restrict__ ids,
                                            const float* __restrict__ W1,
                                            const float* __restrict__ W2,
                                            char* __restrict__ PbF,
                                            char* __restrict__ W1F,
                                            char* __restrict__ W2F) {
    int bid = blockIdx.x;
    int tid = threadIdx.x;
    if (bid < 8192) {
        // pooled[b,i,:] = mean_{j<i, ngram match} H[b,j,:]; deterministic bitmap scan
        int row = bid;
        int i = row & (LSEQ - 1);
        int base = row - i;
        int key_i = key_at(ids, base, i);
        const float4* H4 = (const float4*)H;

        __shared__ unsigned bm[8];
        float4 acc = make_float4(0.f, 0.f, 0.f, 0.f);
        int count = 0;
        for (int j0 = 0; j0 < i; j0 += 256) {
            if (tid < 8) bm[tid] = 0u;
            __syncthreads();
            int j = j0 + tid;
            if (j < i && key_at(ids, base, j) == key_i)
                atomicOr(&bm[tid >> 5], 1u << (tid & 31));
            __syncthreads();
            #pragma unroll
            for (int w = 0; w < 8; ++w) {
                unsigned m = bm[w];
                while (m) {
                    int bit = __ffs(m) - 1;
                    m &= m - 1;
                    int j2 = j0 + w * 32 + bit;
                    count++;
                    float4 h = H4[(size_t)(base + j2) * (DDIM / 4) + tid];
                    acc.x += h.x; acc.y += h.y; acc.z += h.z; acc.w += h.w;
                }
            }
            __syncthreads();
        }
        float s = 1.0f / (float)(count > 0 ? count : 1);
        ushort4 o;
        o.x = f2bf(acc.x * s); o.y = f2bf(acc.y * s);
        o.z = f2bf(acc.z * s); o.w = f2bf(acc.w * s);
        int c = tid * 4;                     // column
        int lane = (row & 31) + ((c >> 3) & 1) * 32;
        *(ushort4*)(PbF + frag_off(row >> 5, c >> 4, lane) + (c & 7) * 2) = o;
    } else {
        // W[K][N] fp32 -> fragment-major bf16 of W^T. 512 blocks: 16(k) x 16(n) x 2
        int b2 = bid - 8192;
        const float* W = (b2 >> 8) ? W2 : W1;
        char* Wf = (b2 >> 8) ? W2F : W1F;
        int r2 = b2 & 255;
        int k0 = (r2 & 15) * 64, n0 = (r2 >> 4) * 64;
        __shared__ ushort t[64][65];
        #pragma unroll
        for (int it = 0; it < 16; ++it) {
            int idx = it * 256 + tid;
            int r = idx >> 6, c = idx & 63;
            t[c][r] = f2bf(W[(size_t)(k0 + r) * DDIM + n0 + c]);   // t[n'][k']
        }
        __syncthreads();
        #pragma unroll
        for (int it = 0; it < 4; ++it) {
            int idx = it * 256 + tid;
            int r = idx >> 4, g = idx & 15;    // n' = r, k' = g*4
            int n = n0 + r, k = k0 + g * 4;
            ushort4 v;
            v.x = t[r][g * 4]; v.y = t[r][g * 4 + 1];
            v.z = t[r][g * 4 + 2]; v.w = t[r][g * 4 + 3];
            int lane = (n & 31) + ((k >> 3) & 1) * 32;
            *(ushort4*)(Wf + frag_off(n >> 5, k >> 4, lane) + (k & 7) * 2) = v;
        }
    }
}

// ---------------- Kernel 2: out = H@W1 + P@W2 + (b1+b2), 32x32x16 bf16 MFMA -------
// ZERO LDS, ZERO barriers. 4 waves/block, each wave owns an INDEPENDENT 64x128
// output tile (2M x 4N frags of 32x32, acc=128 VGPR). A and B fragments are
// per-lane 16B contiguous global loads (fragment-major buffers); H-path A loads
// fp32 per-lane + in-register cvt. 2-slice software pipeline in named registers;
// latency hidden by ILP (loads for slice t+2 issued while slice t computes).
// Grid 256 = 1 block/CU; XCD (bid&7) owns 4 contiguous 256-row slabs x all cols.
__global__ __launch_bounds__(256) void gemm_bf16(
    const float* __restrict__ H,      // [8192][1024] fp32
    const char* __restrict__ PbF,     // pooled, bf16 fragment-major
    const char* __restrict__ W1F,     // W1^T, bf16 fragment-major
    const char* __restrict__ W2F,
    const float* __restrict__ b1,
    const float* __restrict__ b2,
    float* __restrict__ out)          // [8192][1024] fp32
{
    const int tid = threadIdx.x;
    const int lane = tid & 63;
    const int wid = tid >> 6;         // 0..3
    const int l31 = lane & 31;
    const int hi2 = lane >> 5;

    const int bid = blockIdx.x;
    const int j = bid >> 3;                          // 0..31
    const int row0 = ((bid & 7) * 4 + (j & 3)) * 256;
    const int col0 = (j >> 2) * 128;

    const int wrow = row0 + wid * 64;                // wave's 64 rows

    f32x16 acc[2][4];
    #pragma unroll
    for (int mm = 0; mm < 2; ++mm)
        #pragma unroll
        for (int nn = 0; nn < 4; ++nn)
            #pragma unroll
            for (int q = 0; q < 16; ++q) acc[mm][nn][q] = 0.f;

    // per-lane bases
    const float* hp0 = H + (size_t)(wrow + l31) * DDIM + hi2 * 8;       // + mm*32*DDIM + k16*16
    const char* pb = PbF + frag_off(wrow >> 5, 0, lane);                // + (mm*64 + k16)*1024
    const char* w1 = W1F + frag_off(col0 >> 5, 0, lane);                // + (nn*64 + k16)*1024
    const char* w2 = W2F + frag_off(col0 >> 5, 0, lane);

#define LOAD_HA(k16, ra)                                                 \
    ra[0] = *(const float4*)(hp0 + (k16) * 16);                          \
    ra[1] = *(const float4*)(hp0 + (k16) * 16 + 4);                      \
    ra[2] = *(const float4*)(hp0 + 32 * DDIM + (k16) * 16);              \
    ra[3] = *(const float4*)(hp0 + 32 * DDIM + (k16) * 16 + 4);

#define LOAD_PA(k16, aa)                                                 \
    aa[0] = *(const bf16x8*)(pb + (size_t)(k16) * 1024);                 \
    aa[1] = *(const bf16x8*)(pb + (size_t)(64 + (k16)) * 1024);

#define LOAD_B(Wf, k16, bb)                                              \
    bb[0] = *(const bf16x8*)(Wf + (size_t)(k16) * 1024);                 \
    bb[1] = *(const bf16x8*)(Wf + (size_t)(64 + (k16)) * 1024);          \
    bb[2] = *(const bf16x8*)(Wf + (size_t)(128 + (k16)) * 1024);         \
    bb[3] = *(const bf16x8*)(Wf + (size_t)(192 + (k16)) * 1024);

    auto cvt2 = [&](const float4* ra, bf16x8* af) {
        #pragma unroll
        for (int m = 0; m < 2; ++m) {
            bf16x8 v;
            v[0] = (short)f2bf(ra[2 * m].x); v[1] = (short)f2bf(ra[2 * m].y);
            v[2] = (short)f2bf(ra[2 * m].z); v[3] = (short)f2bf(ra[2 * m].w);
            v[4] = (short)f2bf(ra[2 * m + 1].x); v[5] = (short)f2bf(ra[2 * m + 1].y);
            v[6] = (short)f2bf(ra[2 * m + 1].z); v[7] = (short)f2bf(ra[2 * m + 1].w);
            af[m] = v;
        }
    };
    auto mfma8 = [&](bf16x8* af, bf16x8* bb) {
        #pragma unroll
        for (int mm = 0; mm < 2; ++mm)
            #pragma unroll
            for (int nn = 0; nn < 4; ++nn)
                acc[mm][nn] = __builtin_amdgcn_mfma_f32_32x32x16_bf16(
                    af[mm], bb[nn], acc[mm][nn], 0, 0, 0);
    };

    // ---------------- path 0: H @ W1 (64 k16-slices) ----------------
    {
        float4 raA[4], raB[4];
        bf16x8 bA[4], bB[4], afA[2], afB[2];
        LOAD_HA(0, raA); LOAD_B(w1, 0, bA);
        LOAD_HA(1, raB); LOAD_B(w1, 1, bB);
        #pragma unroll 1
        for (int t = 0; t < 62; t += 2) {
            cvt2(raA, afA);
            mfma8(afA, bA);
            LOAD_HA(t + 2, raA); LOAD_B(w1, t + 2, bA);
            cvt2(raB, afB);
            mfma8(afB, bB);
            LOAD_HA(t + 3, raB); LOAD_B(w1, t + 3, bB);
        }
        cvt2(raA, afA); mfma8(afA, bA);
        cvt2(raB, afB); mfma8(afB, bB);
    }

    // ---------------- path 1: P @ W2 (64 k16-slices) ----------------
    {
        bf16x8 aA[2], aB[2], bA[4], bB[4];
        LOAD_PA(0, aA); LOAD_B(w2, 0, bA);
        LOAD_PA(1, aB); LOAD_B(w2, 1, bB);
        #pragma unroll 1
        for (int t = 0; t < 62; t += 2) {
            mfma8(aA, bA);
            LOAD_PA(t + 2, aA); LOAD_B(w2, t + 2, bA);
            mfma8(aB, bB);
            LOAD_PA(t + 3, aB); LOAD_B(w2, t + 3, bB);
        }
        mfma8(aA, bA);
        mfma8(aB, bB);
    }

#undef LOAD_HA
#undef LOAD_PA
#undef LOAD_B

    // epilogue: 32x32 C/D layout col=lane&31, row=(reg&3)+8*(reg>>2)+4*(lane>>5)
    #pragma unroll
    for (int mm = 0; mm < 2; ++mm) {
        #pragma unroll
        for (int nn = 0; nn < 4; ++nn) {
            const int c = col0 + nn * 32 + l31;
            const float bias = b1[c] + b2[c];
            const int rbase = wrow + mm * 32 + hi2 * 4;
            #pragma unroll
            for (int reg = 0; reg < 16; ++reg) {
                int r = rbase + (reg & 3) + 8 * (reg >> 2);
                out[(size_t)r * DDIM + c] = acc[mm][nn][reg] + bias;
            }
        }
    }
}

extern "C" void kernel_launch(void* const* d_in, const int* in_sizes, int n_in,
                              void* d_out, int out_size, void* d_ws, size_t ws_size,
                              hipStream_t stream) {
    const float* H  = (const float*)d_in[0];
    const int*   ids = (const int*)d_in[1];
    const float* W1 = (const float*)d_in[2];
    const float* b1 = (const float*)d_in[3];
    const float* W2 = (const float*)d_in[4];
    const float* b2 = (const float*)d_in[5];
    float* out = (float*)d_out;

    char* ws = (char*)d_ws;
    char* PbF = ws;                      // 16MB bf16 pooled, fragment-major
    char* W1F = ws + (16 << 20);         // 2MB
    char* W2F = ws + (18 << 20);         // 2MB  (total 20MB, proven-safe)

    prep<<<8192 + 512, 256, 0, stream>>>(H, ids, W1, W2, PbF, W1F, W2F);
    gemm_bf16<<<256, 256, 0, stream>>>(H, PbF, W1F, W2F, b1, b2, out);
}